// Round 2
// baseline (42613.940 us; speedup 1.0000x reference)
//
#include <hip/hip_runtime.h>
#include <hip/hip_cooperative_groups.h>
#include <math.h>

namespace cg = cooperative_groups;

#define S 512
#define B 64
#define I 1024
#define HD 1024
#define G4 (4*HD)

typedef _Float16 half8 __attribute__((ext_vector_type(8)));
typedef float floatx4 __attribute__((ext_vector_type(4)));
typedef float f32x4 __attribute__((ext_vector_type(4)));

// ---------- prep kernels ----------

__global__ void cast_f32_to_f16(const float* __restrict__ src,
                                _Float16* __restrict__ dst, long n8) {
    long i = (long)blockIdx.x * blockDim.x + threadIdx.x;
    if (i >= n8) return;
    const f32x4* s = (const f32x4*)src + i * 2;
    f32x4 a = s[0], b = s[1];
    half8 h;
    h[0] = (_Float16)a[0]; h[1] = (_Float16)a[1];
    h[2] = (_Float16)a[2]; h[3] = (_Float16)a[3];
    h[4] = (_Float16)b[0]; h[5] = (_Float16)b[1];
    h[6] = (_Float16)b[2]; h[7] = (_Float16)b[3];
    *((half8*)dst + i) = h;
}

__global__ void init_state(const float* __restrict__ h0,
                           const float* __restrict__ bi, const float* __restrict__ bh,
                           _Float16* __restrict__ hb0, float* __restrict__ bsum) {
    int i = blockIdx.x * blockDim.x + threadIdx.x;
    if (i < B * HD) hb0[i] = (_Float16)h0[i];
    if (i < G4) bsum[i] = bi[i] + bh[i];
}

// ---------- persistent recurrent kernel ----------
// 256 blocks x 256 threads (4 waves), cooperative launch, 1 block/CU.
// Block m: row-group rg=m>>1 owns hidden units j in [rg*8, rg*8+8) (32 W-rows:
// local row r -> gate g=r&3, hidden j=rg*8+(r>>2)); batch-group bg=m&1 owns
// batches [bg*32, bg*32+32).
// Waves: rt=w>>1 row-tile (16 rows), bt=w&1 batch-tile (16 batches).
// MFMA 16x16x32 f16, D lane l: col=l&15 (batch), row=(l>>4)*4+q (q=gate).
// => each lane owns one (batch, hidden) pair with all 4 gates in acc; c stays
// in a register across all 512 steps.

__global__ __launch_bounds__(256) void lstm_persistent(
    const _Float16* __restrict__ xb,   // (S,B,I) f16
    const _Float16* __restrict__ Wib,  // (4H,I)  f16
    const _Float16* __restrict__ Whb,  // (4H,H)  f16
    const float*    __restrict__ bsum, // (4H)
    const float*    __restrict__ c0,   // (B,H) f32
    _Float16*       __restrict__ hb0,  // (B,H) f16 ping
    _Float16*       __restrict__ hb1,  // (B,H) f16 pong
    float*          __restrict__ out)  // (S,B,H) + (B,H) + (B,H) f32
{
    __shared__ _Float16 Wli[32][1032];   // stride 516 words % 32 = 4 -> 2-way alias (free)
    __shared__ _Float16 Wlh[32][1032];

    const int m = blockIdx.x;
    const int rg = m >> 1;
    const int bg = m & 1;
    const int tid = threadIdx.x;
    const int l = tid & 63, w = tid >> 6;
    const int rt = w >> 1, bt = w & 1;

    // Stage this block's 32 rows of Wi and Wh into LDS once.
    for (int idx = tid; idx < 32 * 128; idx += 256) {
        int r = idx >> 7;
        int ch = (idx & 127) * 8;
        int grow = (r & 3) * HD + (rg * 8 + (r >> 2));
        *(half8*)&Wli[r][ch] = *(const half8*)&Wib[(size_t)grow * I + ch];
        *(half8*)&Wlh[r][ch] = *(const half8*)&Whb[(size_t)grow * HD + ch];
    }

    const int bq = bg * 32 + bt * 16 + (l & 15);   // global batch this lane owns
    const int j  = rg * 8 + rt * 4 + (l >> 4);     // global hidden unit
    const int kq = (l >> 4) * 8;                   // k-offset within 32-wide step

    const _Float16* wip = &Wli[rt * 16 + (l & 15)][kq];
    const _Float16* whp = &Wlh[rt * 16 + (l & 15)][kq];

    const float b0 = bsum[j];
    const float b1 = bsum[HD + j];
    const float b2 = bsum[2 * HD + j];
    const float b3 = bsum[3 * HD + j];
    const size_t cix = (size_t)bq * HD + j;
    float c = c0[cix];

    cg::grid_group grid = cg::this_grid();
    __syncthreads();   // weights staged (block-local; xb/h ready via stream order)

    int p = 0;
    for (int t = 0; t < S; ++t) {
        const _Float16* xrow = xb + ((size_t)t * B + bq) * I + kq;
        const _Float16* hrow = (p ? hb1 : hb0) + (size_t)bq * HD + kq;

        floatx4 accx = {0.f, 0.f, 0.f, 0.f};
        floatx4 acch = {0.f, 0.f, 0.f, 0.f};
        #pragma unroll 8
        for (int k = 0; k < 1024; k += 32) {
            half8 ax = *(const half8*)(wip + k);
            half8 bx = *(const half8*)(xrow + k);
            accx = __builtin_amdgcn_mfma_f32_16x16x32_f16(ax, bx, accx, 0, 0, 0);
            half8 ah = *(const half8*)(whp + k);
            half8 bh = *(const half8*)(hrow + k);
            acch = __builtin_amdgcn_mfma_f32_16x16x32_f16(ah, bh, acch, 0, 0, 0);
        }

        float pi = accx[0] + acch[0] + b0;
        float pf = accx[1] + acch[1] + b1;
        float po = accx[2] + acch[2] + b2;
        float pg = accx[3] + acch[3] + b3;

        float ig = 1.f / (1.f + __expf(-pi));
        float fg = 1.f / (1.f + __expf(-pf));
        float og = 1.f / (1.f + __expf(-po));
        float gg = 1.f - 2.f / (__expf(2.f * pg) + 1.f);   // tanh

        c = c * fg + ig * gg;
        float th = 1.f - 2.f / (__expf(2.f * c) + 1.f);    // tanh(c)
        float ht = og * th;

        (p ? hb0 : hb1)[cix] = (_Float16)ht;
        out[((size_t)t * B + bq) * HD + j] = ht;
        if (t == S - 1) {
            out[(size_t)S * B * HD + cix] = ht;                      // h_f
            out[(size_t)S * B * HD + (size_t)B * HD + cix] = c;      // c_f
        }

        __threadfence();   // release h writes (device scope)
        grid.sync();
        __threadfence();   // acquire side: invalidate stale caches
        p ^= 1;
    }
}

// ---------- launch ----------

extern "C" void kernel_launch(void* const* d_in, const int* in_sizes, int n_in,
                              void* d_out, int out_size, void* d_ws, size_t ws_size,
                              hipStream_t stream) {
    const float* x  = (const float*)d_in[0];
    const float* h0 = (const float*)d_in[1];
    const float* c0 = (const float*)d_in[2];
    const float* Wi = (const float*)d_in[3];
    const float* bi = (const float*)d_in[4];
    const float* Wh = (const float*)d_in[5];
    const float* bh = (const float*)d_in[6];
    float* out = (float*)d_out;

    char* p = (char*)d_ws;
    _Float16* xb  = (_Float16*)p; p += (size_t)S * B * I * 2;
    _Float16* Wib = (_Float16*)p; p += (size_t)G4 * I * 2;
    _Float16* Whb = (_Float16*)p; p += (size_t)G4 * HD * 2;
    _Float16* hb0 = (_Float16*)p; p += (size_t)B * HD * 2;
    _Float16* hb1 = (_Float16*)p; p += (size_t)B * HD * 2;
    float* bsum   = (float*)p;    p += (size_t)G4 * 4;

    long nx8 = (long)S * B * I / 8;
    cast_f32_to_f16<<<(int)((nx8 + 255) / 256), 256, 0, stream>>>(x, xb, nx8);
    long nw8 = (long)G4 * I / 8;
    cast_f32_to_f16<<<(int)((nw8 + 255) / 256), 256, 0, stream>>>(Wi, Wib, nw8);
    cast_f32_to_f16<<<(int)((nw8 + 255) / 256), 256, 0, stream>>>(Wh, Whb, nw8);
    init_state<<<(B * HD + 255) / 256, 256, 0, stream>>>(h0, bi, bh, hb0, bsum);

    const float* c0p = c0;
    void* args[] = {(void*)&xb, (void*)&Wib, (void*)&Whb, (void*)&bsum,
                    (void*)&c0p, (void*)&hb0, (void*)&hb1, (void*)&out};
    hipLaunchCooperativeKernel((const void*)lstm_persistent, dim3(256), dim3(256),
                               args, 0, stream);
}

// Round 4
// 6094.517 us; speedup vs baseline: 6.9922x; 6.9922x over previous
//
#include <hip/hip_runtime.h>
#include <math.h>

#define S 512
#define B 64
#define I 1024
#define HD 1024
#define G4 (4*HD)
#define NB 256

typedef _Float16 half8 __attribute__((ext_vector_type(8)));
typedef float floatx4 __attribute__((ext_vector_type(4)));
typedef float f32x4 __attribute__((ext_vector_type(4)));
typedef unsigned uint4v __attribute__((ext_vector_type(4)));
typedef unsigned long long u64x2 __attribute__((ext_vector_type(2)));

// ---------- prep kernels ----------

__global__ void cast_f32_to_f16(const float* __restrict__ src,
                                _Float16* __restrict__ dst, long n8) {
    long i = (long)blockIdx.x * blockDim.x + threadIdx.x;
    if (i >= n8) return;
    const f32x4* s = (const f32x4*)src + i * 2;
    f32x4 a = s[0], b = s[1];
    half8 h;
    h[0] = (_Float16)a[0]; h[1] = (_Float16)a[1];
    h[2] = (_Float16)a[2]; h[3] = (_Float16)a[3];
    h[4] = (_Float16)b[0]; h[5] = (_Float16)b[1];
    h[6] = (_Float16)b[2]; h[7] = (_Float16)b[3];
    *((half8*)dst + i) = h;
}

__global__ void init_state(const float* __restrict__ h0,
                           const float* __restrict__ bi, const float* __restrict__ bh,
                           _Float16* __restrict__ hb0, float* __restrict__ bsum,
                           int* __restrict__ bar) {
    int i = blockIdx.x * blockDim.x + threadIdx.x;
    if (i < B * HD) hb0[i] = (_Float16)h0[i];
    if (i < G4) bsum[i] = bi[i] + bh[i];
    if (i == 0) *bar = 0;
}

// ---------- persistent recurrent kernel ----------
// 256 blocks x 256 threads, 1 block/CU (cooperative: co-residency required).
// Block m: rg=m>>1 owns hidden units [rg*8, rg*8+8); bg=m&1 owns batches
// [bg*32, +32). Waves: rt=w>>1 (row tile), bt=w&1 (batch tile).
// Weights in LDS in MFMA-fragment order: frag[rt][kstep][lane][8] =
// Wrow_local(rt*16+(lane&15))[kstep*32+(lane>>4)*8+e]; local row r ->
// (gate=r&3, hid=rg*8+(r>>2)). Lane-dense 16B LDS reads = conflict-free.
// D lane l: batch col = l&15, row=(l>>4)*4+q -> j = rg*8+rt*4+(l>>4), gate q.
// c stays in a register all 512 steps.
// Cross-XCD h handoff (all compiler-managed, proven-coherent classes):
//   write: u64 atomic exchange (RMW executes at L3)
//   read:  u64 atomic relaxed-agent load (global_load_dwordx2 sc1, L2 bypass)
//   barrier: monotonic relaxed counter; release = vmcnt(0)+syncthreads first;
//   x-projection MFMA chain overlaps the poll.

__global__ __launch_bounds__(256, 1) void lstm_persistent(
    const _Float16* __restrict__ xb,
    const _Float16* __restrict__ Wib,
    const _Float16* __restrict__ Whb,
    const float*    __restrict__ bsum,
    const float*    __restrict__ c0,
    _Float16* __restrict__ hr0,   // ring slot 0 (holds h0 at start)
    _Float16* __restrict__ hr1,
    _Float16* __restrict__ hr2,
    float*          __restrict__ out,
    int*            __restrict__ bar)
{
    __shared__ _Float16 fragWi[32768];   // 64 KB
    __shared__ _Float16 fragWh[32768];   // 64 KB

    const int m = blockIdx.x;
    const int rg = m >> 1;
    const int bg = m & 1;
    const int tid = threadIdx.x;
    const int l = tid & 63, w = tid >> 6;
    const int rt = w >> 1, bt = w & 1;

    // Stage 32 local W rows of Wi and Wh into fragment-order LDS (once).
    for (int idx = tid; idx < 32 * 128; idx += 256) {
        int r_loc = idx >> 7;            // 0..31
        int ch = idx & 127;              // 8-f16 chunk along K
        int rtt = r_loc >> 4, a = r_loc & 15;
        int kstep = ch >> 2, sub = ch & 3;
        int lane = sub * 16 + a;
        int grow = (r_loc & 3) * HD + (rg * 8 + (r_loc >> 2));
        int dst = rtt * 16384 + kstep * 512 + lane * 8;
        *(half8*)&fragWi[dst] = *(const half8*)&Wib[(size_t)grow * I + ch * 8];
        *(half8*)&fragWh[dst] = *(const half8*)&Whb[(size_t)grow * HD + ch * 8];
    }

    const int bq = bg * 32 + bt * 16 + (l & 15);   // batch this lane owns
    const int jq = rg * 8 + rt * 4;                // hidden quad base
    const int j  = jq + (l >> 4);                  // hidden unit
    const int kq = (l >> 4) * 8;                   // k-offset in 32-wide step
    const int fbase = rt * 16384 + l * 8;

    const float b0 = bsum[j];
    const float b1 = bsum[HD + j];
    const float b2 = bsum[2 * HD + j];
    const float b3 = bsum[3 * HD + j];
    const size_t cix = (size_t)bq * HD + j;
    float c = c0[cix];

    __syncthreads();   // weights staged

    int tm = 0;   // t % 3
    for (int t = 0; t < S; ++t) {
        // ---- x-projection chain: barrier-independent, overlaps the poll ----
        const uint4v* xr = (const uint4v*)(xb + ((size_t)t * B + bq) * I + kq);
        floatx4 accx = {0.f, 0.f, 0.f, 0.f};
        #pragma unroll
        for (int kk = 0; kk < 32; ++kk) {
            half8 ax = *(const half8*)&fragWi[fbase + kk * 512];
            half8 bx = __builtin_bit_cast(half8, xr[kk * 4]);
            accx = __builtin_amdgcn_mfma_f32_16x16x32_f16(ax, bx, accx, 0, 0, 0);
        }

        // ---- wait until all blocks released h_t ----
        if (t > 0) {
            if (tid == 0) {
                const int target = NB * t;
                while (__hip_atomic_load(bar, __ATOMIC_RELAXED,
                                         __HIP_MEMORY_SCOPE_AGENT) < target)
                    __builtin_amdgcn_s_sleep(2);
            }
            __syncthreads();
        }

        // ---- h chain: agent-coherent u64 loads (L2 bypass) ----
        const _Float16* hb_r = (tm == 0) ? hr0 : (tm == 1) ? hr1 : hr2;
        const unsigned long long* hquad =
            (const unsigned long long*)hb_r + ((size_t)bq * HD + kq) / 4;
        floatx4 acch = {0.f, 0.f, 0.f, 0.f};
        #pragma unroll
        for (int kk = 0; kk < 32; ++kk) {
            unsigned long long q0 = __hip_atomic_load(hquad + kk * 8,
                __ATOMIC_RELAXED, __HIP_MEMORY_SCOPE_AGENT);
            unsigned long long q1 = __hip_atomic_load(hquad + kk * 8 + 1,
                __ATOMIC_RELAXED, __HIP_MEMORY_SCOPE_AGENT);
            u64x2 hv; hv.x = q0; hv.y = q1;
            half8 bh = __builtin_bit_cast(half8, hv);
            half8 ah = *(const half8*)&fragWh[fbase + kk * 512];
            acch = __builtin_amdgcn_mfma_f32_16x16x32_f16(ah, bh, acch, 0, 0, 0);
        }

        // ---- gates ----
        float pi = accx[0] + acch[0] + b0;
        float pf = accx[1] + acch[1] + b1;
        float po = accx[2] + acch[2] + b2;
        float pg = accx[3] + acch[3] + b3;

        float ig = 1.f / (1.f + __expf(-pi));
        float fg = 1.f / (1.f + __expf(-pf));
        float og = 1.f / (1.f + __expf(-po));
        float gg = 1.f - 2.f / (__expf(2.f * pg) + 1.f);

        c = c * fg + ig * gg;
        float th = 1.f - 2.f / (__expf(2.f * c) + 1.f);
        float ht = og * th;

        // ---- out store: gather 4 hidden units -> one dwordx4 ----
        float v1 = __shfl_xor(ht, 16);
        float v2 = __shfl_xor(ht, 32);
        float v3 = __shfl_xor(ht, 48);
        if ((l >> 4) == 0) {
            f32x4 o = {ht, v1, v2, v3};
            *(f32x4*)&out[((size_t)t * B + bq) * HD + jq] = o;
        }

        if (t == S - 1) {
            out[(size_t)S * B * HD + cix] = ht;                   // h_f
            out[(size_t)S * B * HD + (size_t)B * HD + cix] = c;   // c_f
        } else {
            // ---- h ring write: pack quad to u64, one atomic exchange ----
            unsigned hb16 = (unsigned)__builtin_bit_cast(unsigned short, (_Float16)ht);
            unsigned p16 = (unsigned)__shfl_xor((int)hb16, 16);
            unsigned w0 = hb16 | (p16 << 16);
            unsigned long long p32 = (unsigned)__shfl_xor((int)w0, 32);
            unsigned long long w64 = (unsigned long long)w0 | (p32 << 32);
            _Float16* hb_w = (tm == 0) ? hr1 : (tm == 1) ? hr2 : hr0;
            if ((l >> 4) == 0) {
                unsigned long long* dst =
                    (unsigned long long*)hb_w + ((size_t)bq * HD + jq) / 4;
                __hip_atomic_exchange(dst, w64, __ATOMIC_RELAXED,
                                      __HIP_MEMORY_SCOPE_AGENT);
            }
            asm volatile("" ::: "memory");
            asm volatile("s_waitcnt vmcnt(0)" ::: "memory");  // swaps at L3
            __syncthreads();                                   // whole block done
            if (tid == 0)
                __hip_atomic_fetch_add(bar, 1, __ATOMIC_RELAXED,
                                       __HIP_MEMORY_SCOPE_AGENT);
            asm volatile("" ::: "memory");
        }
        tm = (tm == 2) ? 0 : tm + 1;
    }
}

// ---------- launch ----------

extern "C" void kernel_launch(void* const* d_in, const int* in_sizes, int n_in,
                              void* d_out, int out_size, void* d_ws, size_t ws_size,
                              hipStream_t stream) {
    const float* x  = (const float*)d_in[0];
    const float* h0 = (const float*)d_in[1];
    const float* c0 = (const float*)d_in[2];
    const float* Wi = (const float*)d_in[3];
    const float* bi = (const float*)d_in[4];
    const float* Wh = (const float*)d_in[5];
    const float* bh = (const float*)d_in[6];
    float* out = (float*)d_out;

    char* p = (char*)d_ws;
    _Float16* xb  = (_Float16*)p; p += (size_t)S * B * I * 2;
    _Float16* Wib = (_Float16*)p; p += (size_t)G4 * I * 2;
    _Float16* Whb = (_Float16*)p; p += (size_t)G4 * HD * 2;
    _Float16* hr0 = (_Float16*)p; p += (size_t)B * HD * 2;
    _Float16* hr1 = (_Float16*)p; p += (size_t)B * HD * 2;
    _Float16* hr2 = (_Float16*)p; p += (size_t)B * HD * 2;
    float* bsum   = (float*)p;    p += (size_t)G4 * 4;
    int* bar      = (int*)p;      p += 256;

    long nx8 = (long)S * B * I / 8;
    cast_f32_to_f16<<<(int)((nx8 + 255) / 256), 256, 0, stream>>>(x, xb, nx8);
    long nw8 = (long)G4 * I / 8;
    cast_f32_to_f16<<<(int)((nw8 + 255) / 256), 256, 0, stream>>>(Wi, Wib, nw8);
    cast_f32_to_f16<<<(int)((nw8 + 255) / 256), 256, 0, stream>>>(Wh, Whb, nw8);
    init_state<<<(B * HD + 255) / 256, 256, 0, stream>>>(h0, bi, bh, hr0, bsum, bar);

    const float* c0p = c0;
    void* args[] = {(void*)&xb, (void*)&Wib, (void*)&Whb, (void*)&bsum,
                    (void*)&c0p, (void*)&hr0, (void*)&hr1, (void*)&hr2,
                    (void*)&out, (void*)&bar};
    hipLaunchCooperativeKernel((const void*)lstm_persistent, dim3(NB), dim3(256),
                               args, 0, stream);
}